// Round 1
// baseline (879.313 us; speedup 1.0000x reference)
//
#include <hip/hip_runtime.h>
#include <math.h>

#define NC 25
#define NHID 50
#define NB 32
#define NH 256
#define NW 256
#define NOH 252
#define NOW 252

// ---------------------------------------------------------------------------
// Kernel 1: per-(b,c) plane, compute 9 stats of g = gelu(conv7(x)+bias):
//   T (total sum), R0, R251 (row sums), C0, C251 (col sums),
//   g00, g0R (=g[0][251]), gR0 (=g[251][0]), gRR (=g[251][251])
// conv7: pad=1, K=7 -> output 252x252, iy = oy+ky-1 in [-1,256]
// ---------------------------------------------------------------------------
__global__ __launch_bounds__(256) void stats_kernel(
    const float* __restrict__ x, const float* __restrict__ w7,
    const float* __restrict__ b7, float* __restrict__ stats)
{
    const int plane = blockIdx.x;          // b*NC + c
    const int c = plane % NC;
    const float* xp = x + (size_t)plane * (NH * NW);

    // uniform weights (compiler should scalarize these loads)
    float wgt[49];
#pragma unroll
    for (int i = 0; i < 49; ++i) wgt[i] = w7[c * 49 + i];
    const float bias = b7[c];

    // ring buffer: 32 input rows, 264 wide (input col = lds col - 4)
    __shared__ __attribute__((aligned(16))) float ring[32][264];
    __shared__ double red5[4][5];
    __shared__ float  red4[4][4];

    const int tid  = threadIdx.x;
    const int wave = tid >> 6;
    const int lane = tid & 63;

    // preload input rows -1..4 into slots 31, 0..4
    for (int iy = -1; iy <= 4; ++iy) {
        int slot = iy & 31;
        for (int l = tid; l < 264; l += 256) {
            int ix = l - 4;
            float v = 0.f;
            if (iy >= 0 && ix >= 0 && ix < NW) v = xp[iy * NW + ix];
            ring[slot][l] = v;
        }
    }

    double tot = 0.0, r0 = 0.0, r251 = 0.0, c0s = 0.0, c251s = 0.0;
    float g00 = 0.f, g0R = 0.f, gR0 = 0.f, gRR = 0.f;

#pragma unroll 1
    for (int k = 0; k < 16; ++k) {
        __syncthreads();   // previous compute done before we clobber ring slots
        // load input rows 16k+5 .. 16k+20
        for (int iy = 16 * k + 5; iy <= 16 * k + 20; ++iy) {
            int slot = iy & 31;
            for (int l = tid; l < 264; l += 256) {
                int ix = l - 4;
                float v = 0.f;
                if (iy < NH && ix >= 0 && ix < NW) v = xp[iy * NW + ix];
                ring[slot][l] = v;
            }
        }
        __syncthreads();

        const int oy0 = 16 * k + 4 * wave;   // this wave's first output row
        if (oy0 < NOH && lane < 63) {
            float acc[4][4];                 // [row j][col cc]
#pragma unroll
            for (int j = 0; j < 4; ++j)
#pragma unroll
                for (int cc = 0; cc < 4; ++cc) acc[j][cc] = 0.f;

#pragma unroll
            for (int r = 0; r < 10; ++r) {   // input rows oy0-1 .. oy0+8
                int iy = oy0 - 1 + r;
                int slot = iy & 31;
                const float4 q0 = *(const float4*)&ring[slot][4 * lane + 0];
                const float4 q1 = *(const float4*)&ring[slot][4 * lane + 4];
                const float4 q2 = *(const float4*)&ring[slot][4 * lane + 8];
                const float4 q3 = *(const float4*)&ring[slot][4 * lane + 12];
                float xv[16];
                xv[0]=q0.x; xv[1]=q0.y; xv[2]=q0.z; xv[3]=q0.w;
                xv[4]=q1.x; xv[5]=q1.y; xv[6]=q1.z; xv[7]=q1.w;
                xv[8]=q2.x; xv[9]=q2.y; xv[10]=q2.z; xv[11]=q2.w;
                xv[12]=q3.x; xv[13]=q3.y; xv[14]=q3.z; xv[15]=q3.w;
#pragma unroll
                for (int j = 0; j < 4; ++j) {
                    const int ky = r - j;    // compile-time after unroll
                    if (ky >= 0 && ky <= 6) {
#pragma unroll
                        for (int cc = 0; cc < 4; ++cc) {
                            float s = 0.f;
#pragma unroll
                            for (int kx = 0; kx < 7; ++kx)
                                s += wgt[ky * 7 + kx] * xv[cc + kx + 3];
                            acc[j][cc] += s;
                        }
                    }
                }
            }
            // epilogue: gelu + stats
#pragma unroll
            for (int j = 0; j < 4; ++j) {
                const int oy = oy0 + j;
                if (oy < NOH) {
#pragma unroll
                    for (int cc = 0; cc < 4; ++cc) {
                        const int ox = 4 * lane + cc;   // < 252 since lane<63
                        float h = acc[j][cc] + bias;
                        float g = 0.5f * h * (1.0f + erff(h * 0.70710678118654752f));
                        tot += (double)g;
                        if (oy == 0) {
                            r0 += (double)g;
                            if (ox == 0)   g00 += g;
                            if (ox == 251) g0R += g;
                        }
                        if (oy == 251) {
                            r251 += (double)g;
                            if (ox == 0)   gR0 += g;
                            if (ox == 251) gRR += g;
                        }
                        if (ox == 0)   c0s   += (double)g;
                        if (ox == 251) c251s += (double)g;
                    }
                }
            }
        }
    }

    // block reduction of 9 values
    double v5[5] = {tot, r0, r251, c0s, c251s};
    float  v4[4] = {g00, g0R, gR0, gRR};
#pragma unroll
    for (int i = 0; i < 5; ++i) {
        double v = v5[i];
        for (int off = 32; off > 0; off >>= 1) v += __shfl_down(v, off, 64);
        v5[i] = v;
    }
#pragma unroll
    for (int i = 0; i < 4; ++i) {
        float v = v4[i];
        for (int off = 32; off > 0; off >>= 1) v += __shfl_down(v, off, 64);
        v4[i] = v;
    }
    __syncthreads();
    if (lane == 0) {
#pragma unroll
        for (int i = 0; i < 5; ++i) red5[wave][i] = v5[i];
#pragma unroll
        for (int i = 0; i < 4; ++i) red4[wave][i] = v4[i];
    }
    __syncthreads();
    if (tid == 0) {
        float* st = stats + (size_t)plane * 9;
#pragma unroll
        for (int i = 0; i < 5; ++i)
            st[i] = (float)(red5[0][i] + red5[1][i] + red5[2][i] + red5[3][i]);
#pragma unroll
        for (int i = 0; i < 4; ++i)
            st[5 + i] = red4[0][i] + red4[1][i] + red4[2][i] + red4[3][i];
    }
}

// ---------------------------------------------------------------------------
// Kernel 2: per-batch. Reconstruct mean of conv3 from stats, run MLP,
// sigmoid+gate, rank channels (stable desc), write idx (as float) and the
// gather table (src channel + gate per output slot).
// ---------------------------------------------------------------------------
__global__ __launch_bounds__(64) void mlp_kernel(
    const float* __restrict__ stats, const float* __restrict__ w3,
    const float* __restrict__ fc1w, const float* __restrict__ fc1b,
    const float* __restrict__ fc2w, const float* __restrict__ fc2b,
    float* __restrict__ idx_out, float* __restrict__ gate_ws,
    int* __restrict__ src_ws)
{
    const int b = blockIdx.x;
    const int t = threadIdx.x;
    __shared__ float mean_s[NC], hid_s[NHID], s_s[NC];

    if (t < NC) {
        const float* st = stats + (size_t)(b * NC + t) * 9;
        float T = st[0], R0 = st[1], R251 = st[2], C0 = st[3], C251 = st[4];
        float g00 = st[5], g0R = st[6], gR0 = st[7], gRR = st[8];
        // excluded row-sum per ky, excluded col-sum per kx
        float ER[3] = {R251, 0.f, R0};
        float EC[3] = {C251, 0.f, C0};
        float CR[3][3] = {{gRR, 0.f, gR0}, {0.f, 0.f, 0.f}, {g0R, 0.f, g00}};
        float m = 0.f;
#pragma unroll
        for (int ky = 0; ky < 3; ++ky)
#pragma unroll
            for (int kx = 0; kx < 3; ++kx) {
                float S = T - ER[ky] - EC[kx] + CR[ky][kx];
                m += w3[t * 9 + ky * 3 + kx] * S;
            }
        mean_s[t] = m * (1.0f / (252.0f * 252.0f));
    }
    __syncthreads();
    if (t < NHID) {
        float a = fc1b[t];
#pragma unroll
        for (int cc = 0; cc < NC; ++cc) a += mean_s[cc] * fc1w[t * NC + cc];
        hid_s[t] = fmaxf(a, 0.f);
    }
    __syncthreads();
    if (t < NC) {
        float a = fc2b[t];
#pragma unroll
        for (int j = 0; j < NHID; ++j) a += hid_s[j] * fc2w[t * NHID + j];
        s_s[t] = 1.0f / (1.0f + expf(-a));
    }
    __syncthreads();
    if (t < NC) {
        float s = s_s[t];
        int rank = 0;
        for (int c2 = 0; c2 < NC; ++c2) {
            float s2 = s_s[c2];
            if (s2 > s || (s2 == s && c2 < t)) rank++;
        }
        float gate = (s * s) / (s * s + 1e-8f);
        idx_out[b * NC + rank] = (float)t;
        gate_ws[b * NC + rank] = gate;
        src_ws[b * NC + rank]  = t;
    }
}

// ---------------------------------------------------------------------------
// Kernel 3: gather + scale + write.
// Output slot j of batch b comes from channel src_ws[b*25+j] scaled by gate.
// Slots 0..9  -> x_selected at out + (b*10 + j)*65536
// Slots 10..24-> x_plug at out + 32*10*65536 + (b*15 + (j-10))*65536
// ---------------------------------------------------------------------------
__global__ __launch_bounds__(256) void gather_kernel(
    const float* __restrict__ x, const float* __restrict__ gate_ws,
    const int* __restrict__ src_ws, float* __restrict__ out)
{
    const int p = blockIdx.x;            // b*25 + j
    const int b = p / NC;
    const int j = p % NC;
    const int src = src_ws[p];
    const float gate = gate_ws[p];

    const float4* xp = (const float4*)(x + ((size_t)(b * NC + src)) * (NH * NW));
    float* dst;
    if (j < 10) dst = out + ((size_t)(b * 10 + j)) * (NH * NW);
    else dst = out + (size_t)NB * 10 * (NH * NW) + ((size_t)(b * 15 + (j - 10))) * (NH * NW);
    float4* dp = (float4*)dst;

    const int t = threadIdx.x;
#pragma unroll 4
    for (int i = t; i < (NH * NW) / 4; i += 256) {
        float4 v = xp[i];
        v.x *= gate; v.y *= gate; v.z *= gate; v.w *= gate;
        dp[i] = v;
    }
}

extern "C" void kernel_launch(void* const* d_in, const int* in_sizes, int n_in,
                              void* d_out, int out_size, void* d_ws, size_t ws_size,
                              hipStream_t stream)
{
    const float* x    = (const float*)d_in[0];
    const float* w7   = (const float*)d_in[1];
    const float* b7   = (const float*)d_in[2];
    const float* w3   = (const float*)d_in[3];
    const float* fc1w = (const float*)d_in[4];
    const float* fc1b = (const float*)d_in[5];
    const float* fc2w = (const float*)d_in[6];
    const float* fc2b = (const float*)d_in[7];
    float* out = (float*)d_out;

    float* stats   = (float*)d_ws;            // 800*9 floats
    float* gate_ws = stats + 800 * 9;         // 800 floats
    int*   src_ws  = (int*)(gate_ws + 800);   // 800 ints

    // idx output tail: after x_selected (32*10*65536) + x_plug (32*15*65536)
    float* idx_out = out + (size_t)NB * 10 * (NH * NW) + (size_t)NB * 15 * (NH * NW);

    stats_kernel<<<NB * NC, 256, 0, stream>>>(x, w7, b7, stats);
    mlp_kernel<<<NB, 64, 0, stream>>>(stats, w3, fc1w, fc1b, fc2w, fc2b,
                                      idx_out, gate_ws, src_ws);
    gather_kernel<<<NB * NC, 256, 0, stream>>>(x, gate_ws, src_ws, out);
}

// Round 2
// 519.579 us; speedup vs baseline: 1.6924x; 1.6924x over previous
//
#include <hip/hip_runtime.h>
#include <math.h>

#define NC 25
#define NHID 50
#define NB 32
#define NH 256
#define NW 256
#define NOH 252
#define NOW 252

#define CHUNK 28          // output rows per block
#define NCHUNK 9          // 9*28 = 252
#define INROWS 34         // CHUNK + 6 input rows (iy = r0-1 .. r0+32)

// ---------------------------------------------------------------------------
// conv pass: NR consecutive output rows starting at ring-local row `lbase+1`
// (lbase = first input row local index). Lane L covers output cols 4L..4L+3.
// Needs ring cols [4L+3 .. 4L+12] per input row.
// ---------------------------------------------------------------------------
template<int NR>
__device__ __forceinline__ void conv_pass(
    const float (*ring)[264], const float* wgt, int lbase, int lane,
    float (*acc)[4])
{
#pragma unroll
    for (int r = 0; r < NR + 6; ++r) {
        const float* rp = &ring[lbase + r][4 * lane];
        float xv[13];
        xv[3] = rp[3];
        const float4 q1 = *(const float4*)(rp + 4);
        const float4 q2 = *(const float4*)(rp + 8);
        xv[4] = q1.x; xv[5] = q1.y; xv[6] = q1.z; xv[7] = q1.w;
        xv[8] = q2.x; xv[9] = q2.y; xv[10] = q2.z; xv[11] = q2.w;
        xv[12] = rp[12];
#pragma unroll
        for (int j = 0; j < NR; ++j) {
            const int ky = r - j;
            if (ky >= 0 && ky < 7) {
#pragma unroll
                for (int cc = 0; cc < 4; ++cc) {
                    float s = 0.f;
#pragma unroll
                    for (int kx = 0; kx < 7; ++kx)
                        s = fmaf(wgt[ky * 7 + kx], xv[cc + kx + 3], s);
                    acc[j][cc] += s;
                }
            }
        }
    }
}

// ---------------------------------------------------------------------------
// Kernel 1: one block per (plane, chunk). Computes partial 9-stats of
// g = gelu(conv7(x)+bias) over output rows [chunk*28, chunk*28+28).
// stats: T, R0, R251, C0, C251, g00, g0R, gR0, gRR  (zero where not in chunk)
// ---------------------------------------------------------------------------
__global__ __launch_bounds__(256) void stats_kernel(
    const float* __restrict__ x, const float* __restrict__ w7,
    const float* __restrict__ b7, float* __restrict__ partial)
{
    const int bid   = blockIdx.x;       // plane*NCHUNK + chunk
    const int plane = bid / NCHUNK;
    const int chunk = bid - plane * NCHUNK;
    const int c     = plane % NC;
    const int r0    = chunk * CHUNK;
    const float* xp = x + (size_t)plane * (NH * NW);

    float wgt[49];
#pragma unroll
    for (int i = 0; i < 49; ++i) wgt[i] = w7[c * 49 + i];
    const float bias = b7[c];

    __shared__ __attribute__((aligned(16))) float ring[INROWS][264];
    __shared__ float red[4][9];

    const int tid  = threadIdx.x;
    const int wave = tid >> 6;
    const int lane = tid & 63;

    // ---- stage all INROWS input rows, float4 per thread, one barrier ----
    // ring col l <-> input col l-4. part p writes ring cols [4p,4p+4) i.e.
    // input cols [4p-4, 4p): p in [1,64] are interior aligned float4 loads.
    for (int idx = tid; idx < INROWS * 66; idx += 256) {
        const int row = idx / 66;
        const int p   = idx - row * 66;
        const int iy  = r0 - 1 + row;
        float4 v = make_float4(0.f, 0.f, 0.f, 0.f);
        if (p >= 1 && p <= 64 && iy >= 0 && iy < NH)
            v = *(const float4*)&xp[iy * NW + 4 * (p - 1)];
        *(float4*)&ring[row][4 * p] = v;
    }
    __syncthreads();

    // ---- compute: wave handles output rows r0 + wave*7 + [0,7) ----
    float tot = 0.f, r0s = 0.f, r251s = 0.f, c0s = 0.f, c251s = 0.f;
    float g00 = 0.f, g0R = 0.f, gR0 = 0.f, gRR = 0.f;

    if (lane < 63) {
        const int oyF0 = r0 + wave * 7;        // pass A: rows oyF0..+3
        const int oyF1 = oyF0 + 4;             // pass B: rows oyF1..+2

        // pass A (4 rows)
        {
            float acc[4][4];
#pragma unroll
            for (int j = 0; j < 4; ++j)
#pragma unroll
                for (int cc = 0; cc < 4; ++cc) acc[j][cc] = 0.f;
            conv_pass<4>(ring, wgt, oyF0 - r0, lane, acc);
#pragma unroll
            for (int j = 0; j < 4; ++j) {
                const int oy = oyF0 + j;
                float g[4];
#pragma unroll
                for (int cc = 0; cc < 4; ++cc) {
                    float h = acc[j][cc] + bias;
                    g[cc] = 0.5f * h * (1.0f + erff(h * 0.70710678f));
                }
                const float s4 = (g[0] + g[1]) + (g[2] + g[3]);
                tot += s4;
                if (lane == 0)  c0s   += g[0];
                if (lane == 62) c251s += g[3];
                if (oy == 0)   { r0s   += s4; if (lane == 0) g00 += g[0]; if (lane == 62) g0R += g[3]; }
                if (oy == 251) { r251s += s4; if (lane == 0) gR0 += g[0]; if (lane == 62) gRR += g[3]; }
            }
        }
        // pass B (3 rows)
        {
            float acc[3][4];
#pragma unroll
            for (int j = 0; j < 3; ++j)
#pragma unroll
                for (int cc = 0; cc < 4; ++cc) acc[j][cc] = 0.f;
            conv_pass<3>(ring, wgt, oyF1 - r0, lane, acc);
#pragma unroll
            for (int j = 0; j < 3; ++j) {
                const int oy = oyF1 + j;
                float g[4];
#pragma unroll
                for (int cc = 0; cc < 4; ++cc) {
                    float h = acc[j][cc] + bias;
                    g[cc] = 0.5f * h * (1.0f + erff(h * 0.70710678f));
                }
                const float s4 = (g[0] + g[1]) + (g[2] + g[3]);
                tot += s4;
                if (lane == 0)  c0s   += g[0];
                if (lane == 62) c251s += g[3];
                if (oy == 0)   { r0s   += s4; if (lane == 0) g00 += g[0]; if (lane == 62) g0R += g[3]; }
                if (oy == 251) { r251s += s4; if (lane == 0) gR0 += g[0]; if (lane == 62) gRR += g[3]; }
            }
        }
    }

    // ---- block reduction of the 9 stats ----
    float st[9] = {tot, r0s, r251s, c0s, c251s, g00, g0R, gR0, gRR};
#pragma unroll
    for (int i = 0; i < 9; ++i) {
        float v = st[i];
        for (int off = 32; off > 0; off >>= 1) v += __shfl_down(v, off, 64);
        st[i] = v;
    }
    if (lane == 0) {
#pragma unroll
        for (int i = 0; i < 9; ++i) red[wave][i] = st[i];
    }
    __syncthreads();
    if (tid < 9)
        partial[(size_t)bid * 9 + tid] =
            (red[0][tid] + red[1][tid]) + (red[2][tid] + red[3][tid]);
}

// ---------------------------------------------------------------------------
// Kernel 2: per-batch. Sum chunk partials (fixed order -> deterministic),
// reconstruct conv3 mean via inclusion-exclusion, MLP, sigmoid, rank.
// ---------------------------------------------------------------------------
__global__ __launch_bounds__(64) void mlp_kernel(
    const float* __restrict__ partial, const float* __restrict__ w3,
    const float* __restrict__ fc1w, const float* __restrict__ fc1b,
    const float* __restrict__ fc2w, const float* __restrict__ fc2b,
    float* __restrict__ idx_out, float* __restrict__ gate_ws,
    int* __restrict__ src_ws)
{
    const int b = blockIdx.x;
    const int t = threadIdx.x;
    __shared__ float mean_s[NC], hid_s[NHID], s_s[NC];

    if (t < NC) {
        const float* base = partial + (size_t)(b * NC + t) * NCHUNK * 9;
        double acc[9];
#pragma unroll
        for (int i = 0; i < 9; ++i) acc[i] = 0.0;
        for (int ch = 0; ch < NCHUNK; ++ch)
#pragma unroll
            for (int i = 0; i < 9; ++i) acc[i] += (double)base[ch * 9 + i];

        float T = (float)acc[0], R0 = (float)acc[1], R251 = (float)acc[2];
        float C0 = (float)acc[3], C251 = (float)acc[4];
        float g00 = (float)acc[5], g0R = (float)acc[6];
        float gR0 = (float)acc[7], gRR = (float)acc[8];

        float ER[3] = {R251, 0.f, R0};
        float EC[3] = {C251, 0.f, C0};
        float CR[3][3] = {{gRR, 0.f, gR0}, {0.f, 0.f, 0.f}, {g0R, 0.f, g00}};
        float m = 0.f;
#pragma unroll
        for (int ky = 0; ky < 3; ++ky)
#pragma unroll
            for (int kx = 0; kx < 3; ++kx) {
                float S = T - ER[ky] - EC[kx] + CR[ky][kx];
                m += w3[t * 9 + ky * 3 + kx] * S;
            }
        mean_s[t] = m * (1.0f / (252.0f * 252.0f));
    }
    __syncthreads();
    if (t < NHID) {
        float a = fc1b[t];
#pragma unroll
        for (int cc = 0; cc < NC; ++cc) a += mean_s[cc] * fc1w[t * NC + cc];
        hid_s[t] = fmaxf(a, 0.f);
    }
    __syncthreads();
    if (t < NC) {
        float a = fc2b[t];
#pragma unroll
        for (int j = 0; j < NHID; ++j) a += hid_s[j] * fc2w[t * NHID + j];
        s_s[t] = 1.0f / (1.0f + expf(-a));
    }
    __syncthreads();
    if (t < NC) {
        float s = s_s[t];
        int rank = 0;
        for (int c2 = 0; c2 < NC; ++c2) {
            float s2 = s_s[c2];
            if (s2 > s || (s2 == s && c2 < t)) rank++;
        }
        float gate = (s * s) / (s * s + 1e-8f);
        idx_out[b * NC + rank] = (float)t;
        gate_ws[b * NC + rank] = gate;
        src_ws[b * NC + rank]  = t;
    }
}

// ---------------------------------------------------------------------------
// Kernel 3: gather + scale. 4 segment-blocks per output slot.
// ---------------------------------------------------------------------------
__global__ __launch_bounds__(256) void gather_kernel(
    const float* __restrict__ x, const float* __restrict__ gate_ws,
    const int* __restrict__ src_ws, float* __restrict__ out)
{
    const int bid = blockIdx.x;
    const int seg = bid & 3;
    const int p   = bid >> 2;            // b*25 + j
    const int b   = p / NC;
    const int j   = p - b * NC;
    const int src = src_ws[p];
    const float gate = gate_ws[p];

    const float4* xp = (const float4*)(x + ((size_t)(b * NC + src)) * (NH * NW))
                       + seg * 4096;
    float* dst;
    if (j < 10) dst = out + ((size_t)(b * 10 + j)) * (NH * NW);
    else dst = out + (size_t)NB * 10 * (NH * NW) + ((size_t)(b * 15 + (j - 10))) * (NH * NW);
    float4* dp = (float4*)dst + seg * 4096;

    const int t = threadIdx.x;
#pragma unroll 4
    for (int i = t; i < 4096; i += 256) {
        float4 v = xp[i];
        v.x *= gate; v.y *= gate; v.z *= gate; v.w *= gate;
        dp[i] = v;
    }
}

extern "C" void kernel_launch(void* const* d_in, const int* in_sizes, int n_in,
                              void* d_out, int out_size, void* d_ws, size_t ws_size,
                              hipStream_t stream)
{
    const float* x    = (const float*)d_in[0];
    const float* w7   = (const float*)d_in[1];
    const float* b7   = (const float*)d_in[2];
    const float* w3   = (const float*)d_in[3];
    const float* fc1w = (const float*)d_in[4];
    const float* fc1b = (const float*)d_in[5];
    const float* fc2w = (const float*)d_in[6];
    const float* fc2b = (const float*)d_in[7];
    float* out = (float*)d_out;

    float* partial = (float*)d_ws;                        // 800*9*9 floats
    float* gate_ws = partial + NB * NC * NCHUNK * 9;      // 800 floats
    int*   src_ws  = (int*)(gate_ws + NB * NC);           // 800 ints

    float* idx_out = out + (size_t)NB * 10 * (NH * NW) + (size_t)NB * 15 * (NH * NW);

    stats_kernel<<<NB * NC * NCHUNK, 256, 0, stream>>>(x, w7, b7, partial);
    mlp_kernel<<<NB, 64, 0, stream>>>(partial, w3, fc1w, fc1b, fc2w, fc2b,
                                      idx_out, gate_ws, src_ws);
    gather_kernel<<<NB * NC * 4, 256, 0, stream>>>(x, gate_ws, src_ws, out);
}